// Round 17
// baseline (44.993 us; speedup 1.0000x reference)
//
#include <hip/hip_runtime.h>
#include <hip/hip_bf16.h>
#include <cstdint>

// GraphLoss: layered lattice DAG (64 layers x 64 nodes, dense bipartite).
// result = sum(w*gold) + logsumexp over all source->sink paths of (-path weight).
//
// R17 = R16's ring architecture + PROVEN math only.
// Evidence: every v_dot2_f32_bf16 kernel failed (R6 3.0, R10 4.25, R16 4.25,
// deterministic); every f32-u unpack+pk_fma kernel passed (R5/7/8/11/13/14/15,
// absmax 0.0). So: consumer = R5's byte-identical unpack+fma COMPUTE with W
// from the LDS ring; u kept in f32 LDS; renorm = R11's u=p*rcp(rho),
// LS += log(rho) (proven).
//  * consumer wave 0: lane = node b, full 64-term dot -> NO barrier/shfl
//    per level; NO vmcnt ever (per-wave counters isolate it from producers).
//  * producers waves 1-3: only global_load_lds (LDS targets, no reg hazards);
//    counted vmcnt(8) fenced by sched_barrier(0) BOTH sides; producers issue
//    no other VMEM so the count is exact by construction.
//  * 16-slot ring (128KB), write-once LDS flags + done counter (LDS state:
//    fresh every launch, replay-safe).
//
// Edge layout: e in [0,64): source->layer1 ; e = 64 + L*4096 + a*64 + b ;
// e = 258112 + j: layer64 node j -> sink.

typedef float v2f   __attribute__((ext_vector_type(2)));
typedef float f32x4 __attribute__((ext_vector_type(4)));
typedef unsigned int u32x4 __attribute__((ext_vector_type(4)));
typedef __attribute__((address_space(3))) unsigned int as3_u32;
typedef __attribute__((address_space(1))) const unsigned int as1_u32;

#define NLV 63
#define RING 16
#define NPACK (63 * 2048)            // packed u32 words (8KB/level)
#define SINK_BASE (64 + 63 * 4096)   // 258112
#define NPB 256

// ---------------------------------------------------------------------------
// prep (R5 verbatim, proven absmax 0.0): wpk[f] packs
//   bf16(exp(-w[e0])) | bf16(exp(-w[e1]))<<16,
//   f = l*2048 + c*256 + b*4 + d, a0 = 8c+2d, e0 = 64+l*4096+a0*64+b, e1=e0+64.
// Consumer lane b reads u32x4 at word l*2048 + q*256 + b*4 (q=0..7): pairs
// (8q+2d, 8q+2d+1) -> u-quad words 8q..8q+7 (two f32x4). 1KB coalesced/read.
// Plus 256 block partials of sum(w*gold).
__global__ __launch_bounds__(512)
void prep_kernel(const int* __restrict__ g, const float* __restrict__ w,
                 unsigned int* __restrict__ wpk, float* __restrict__ partial, int E) {
    const int f = blockIdx.x * blockDim.x + threadIdx.x;
    if (f < NPACK) {
        const int d = f & 3;
        const int b = (f >> 2) & 63;
        const int c = (f >> 8) & 7;
        const int l = f >> 11;
        const int a0 = 8 * c + 2 * d;
        const int e0 = 64 + l * 4096 + a0 * 64 + b;
        const float x0 = __expf(-w[e0]);
        const float x1 = __expf(-w[e0 + 64]);
        uint32_t u0 = __float_as_uint(x0); u0 = (u0 + 0x7fffu + ((u0 >> 16) & 1u)) >> 16;
        uint32_t u1 = __float_as_uint(x1); u1 = (u1 + 0x7fffu + ((u1 >> 16) & 1u)) >> 16;
        wpk[f] = u0 | (u1 << 16);
    }
    const bool is64 = (g[1] == 0);
    float s = 0.f;
    const int stride = gridDim.x * blockDim.x;
    for (int e = f; e < E; e += stride) {
        const int idx = 3 * e + 2;
        const int gv = is64 ? g[2 * idx] : g[idx];
        s += w[e] * (float)gv;
    }
    #pragma unroll
    for (int dd = 1; dd < 64; dd <<= 1) s += __shfl_xor(s, dd, 64);
    __shared__ float lsm[8];
    const int wv = threadIdx.x >> 6, ln = threadIdx.x & 63;
    if (ln == 0) lsm[wv] = s;
    __syncthreads();
    if (threadIdx.x == 0) {
        float tt = 0.f;
        #pragma unroll
        for (int i = 0; i < 8; ++i) tt += lsm[i];
        partial[blockIdx.x] = tt;
    }
}

// ---------------------------------------------------------------------------
// seq: 256 threads. wave 0 = consumer (lane = node b); waves 1-3 = producers.
__global__ __launch_bounds__(256, 1)
void seq_kernel(const float* __restrict__ w, const unsigned int* __restrict__ wpk,
                const float* __restrict__ partial, float* __restrict__ out) {
    __shared__ __align__(16) unsigned int wring[RING * 2048];  // 128KB W ring
    __shared__ __align__(16) float ubuf[2][64];                // f32 u dbuf
    __shared__ unsigned int flags[64];                         // write-once per level
    __shared__ unsigned int done;                              // consumer progress

    const int tid = threadIdx.x;
    const int wv = tid >> 6, l = tid & 63;

    if (tid < 64) flags[tid] = 0u;
    if (tid == 0) done = 0u;
    __syncthreads();   // before any VMEM: safe

#define PISSUE(T) do {                                                         \
    const unsigned int* gsrc = wpk + (T) * 2048 + (l << 2);                    \
    unsigned int* ldst = &wring[((T) & 15) * 2048];                            \
    _Pragma("unroll")                                                          \
    for (int q = 0; q < 8; ++q)                                                \
        __builtin_amdgcn_global_load_lds((as1_u32*)(gsrc + (q << 8)),          \
                                         (as3_u32*)(ldst + (q << 8)), 16, 0, 0);\
} while (0)

    if (wv != 0) {
        // ---------- producer p = wv-1: levels p, p+3, p+6, ... ----------
        const int p = wv - 1;
        PISSUE(p);
        PISSUE(p + 3);
        __builtin_amdgcn_sched_barrier(0);
        asm volatile("s_waitcnt vmcnt(8)" ::: "memory");   // level p landed
        __builtin_amdgcn_sched_barrier(0);
        if (l == 0)
            __hip_atomic_store(&flags[p], 1u, __ATOMIC_RELEASE, __HIP_MEMORY_SCOPE_WORKGROUP);
        int last = p + 3;
        #pragma unroll 1
        for (int t = p + 6; t <= 62; t += 3) {
            while ((int)__hip_atomic_load(&done, __ATOMIC_RELAXED,
                                          __HIP_MEMORY_SCOPE_WORKGROUP) + 15 < t)
                __builtin_amdgcn_s_sleep(1);
            PISSUE(t);
            __builtin_amdgcn_sched_barrier(0);
            asm volatile("s_waitcnt vmcnt(8)" ::: "memory");   // level t-3 landed
            __builtin_amdgcn_sched_barrier(0);
            if (l == 0)
                __hip_atomic_store(&flags[t - 3], 1u, __ATOMIC_RELEASE,
                                   __HIP_MEMORY_SCOPE_WORKGROUP);
            last = t;
        }
        __builtin_amdgcn_sched_barrier(0);
        asm volatile("s_waitcnt vmcnt(0)" ::: "memory");       // drain final level
        __builtin_amdgcn_sched_barrier(0);
        if (l == 0)
            __hip_atomic_store(&flags[last], 1u, __ATOMIC_RELEASE,
                               __HIP_MEMORY_SCOPE_WORKGROUP);
        return;
    }

    // ---------- consumer (wave 0), lane l = node b ----------
    const float z1 = -w[l];
    float LS = __int_as_float(__builtin_amdgcn_readfirstlane(__float_as_int(z1)));
    float uf = __expf(z1 - LS);                    // u_1, u_1[0] = 1
    const float wsink = w[SINK_BASE + l];
    float gs = 0.f;
    #pragma unroll
    for (int i = 0; i < 4; ++i) gs += partial[l + (i << 6)];
    ubuf[0][l] = uf;

    #pragma unroll 1
    for (int t = 0; t < NLV; ++t) {
        while (__hip_atomic_load(&flags[t], __ATOMIC_ACQUIRE,
                                 __HIP_MEMORY_SCOPE_WORKGROUP) == 0u)
            __builtin_amdgcn_s_sleep(0);
        const unsigned int* wslot = &wring[(t & 15) * 2048];
        const f32x4* uq4 = (const f32x4*)&ubuf[t & 1][0];
        // R5-proven unpack + pk_fma core (c = q chunk over a-pairs)
        v2f acc0 = {0.f, 0.f}, acc1 = {0.f, 0.f};
        #pragma unroll
        for (int c = 0; c < 8; ++c) {
            const u32x4 wc = *(const u32x4*)&wslot[(c << 8) + (l << 2)];
            const f32x4 ua = uq4[2 * c];
            const f32x4 ub = uq4[2 * c + 1];
            v2f w0, w1, w2, w3, u01, u23, u45, u67;
            w0[0] = __uint_as_float(wc[0] << 16);
            w0[1] = __uint_as_float(wc[0] & 0xffff0000u);
            w1[0] = __uint_as_float(wc[1] << 16);
            w1[1] = __uint_as_float(wc[1] & 0xffff0000u);
            w2[0] = __uint_as_float(wc[2] << 16);
            w2[1] = __uint_as_float(wc[2] & 0xffff0000u);
            w3[0] = __uint_as_float(wc[3] << 16);
            w3[1] = __uint_as_float(wc[3] & 0xffff0000u);
            u01[0] = ua[0]; u01[1] = ua[1]; u23[0] = ua[2]; u23[1] = ua[3];
            u45[0] = ub[0]; u45[1] = ub[1]; u67[0] = ub[2]; u67[1] = ub[3];
            acc0 = __builtin_elementwise_fma(w0, u01, acc0);
            acc1 = __builtin_elementwise_fma(w1, u23, acc1);
            acc0 = __builtin_elementwise_fma(w2, u45, acc0);
            acc1 = __builtin_elementwise_fma(w3, u67, acc1);
        }
        const v2f at = acc0 + acc1;
        const float p = at[0] + at[1];             // full 64-term dot for b=l
        const float rho = __int_as_float(__builtin_amdgcn_readfirstlane(__float_as_int(p)));
        float rc;
        asm("v_rcp_f32 %0, %1" : "=v"(rc) : "v"(rho));
        uf = p * rc;                               // u_next, u_next[0] = 1
        LS += __logf(rho);                         // off critical path
        ubuf[(t + 1) & 1][l] = uf;
        __hip_atomic_store(&done, (unsigned)(t + 1), __ATOMIC_RELEASE,
                           __HIP_MEMORY_SCOPE_WORKGROUP);
    }

    // sink fold: m[b] = LS + log(uf) - wsink; lsexp over b; + gold
    float m = LS + __logf(uf) - wsink;
    float s = 1.0f;
    #pragma unroll
    for (int d = 1; d < 64; d <<= 1) {
        const float om = __shfl_xor(m, d, 64);
        const float os = __shfl_xor(s, d, 64);
        const float nm = fmaxf(m, om);
        s = __expf(m - nm) * s + __expf(om - nm) * os;
        m = nm;
    }
    const float vsink = m + __logf(s);

    #pragma unroll
    for (int d = 1; d < 64; d <<= 1) gs += __shfl_xor(gs, d, 64);

    if (l == 0) out[0] = gs + vsink;
}

extern "C" void kernel_launch(void* const* d_in, const int* in_sizes, int n_in,
                              void* d_out, int out_size, void* d_ws, size_t ws_size,
                              hipStream_t stream) {
    const int*   g = (const int*)d_in[0];
    const float* w = (const float*)d_in[1];
    float* out     = (float*)d_out;
    unsigned int* wpk = (unsigned int*)d_ws;        // 129024 u32
    float* partial = (float*)(wpk + NPACK);         // 256 floats
    const int E = in_sizes[0] / 3;                  // 258176

    prep_kernel<<<NPB, 512, 0, stream>>>(g, w, wpk, partial, E);
    seq_kernel<<<1, 256, 0, stream>>>(w, wpk, partial, out);
}

// Round 18
// 28.132 us; speedup vs baseline: 1.5993x; 1.5993x over previous
//
#include <hip/hip_runtime.h>
#include <hip/hip_bf16.h>
#include <cstdint>

// GraphLoss: layered lattice DAG (64 layers x 64 nodes, dense bipartite).
// result = sum(w*gold) + logsumexp over all source->sink paths of (-path weight).
//
// R18 = R14 (champion, 28.3us) + ONE body change: u/rho LDS reads hoisted
// ABOVE the counted vmcnt wait, so their ~150cy LDS latency overlaps the
// W-prefetch stall instead of following it serially. ds_reads can't sink
// below the "memory"-clobber vmcnt asm; fmas stay below via the "+v" pin's
// data dependence (R14-proven pattern). ubuf/P writes moved before the
// off-path log. All arithmetic bit-identical to R14 (absmax 0.0 expected).
//
// Structure (all R14-proven): depth-10 register pipeline of bf16-packed W
// (inline-asm global_load_dwordx4, counted vmcnt 18/16/../0 peeled tail,
// ZERO in flight at exit, no dummy loads, sched_barrier fences, raw
// s_barrier + lgkmcnt(0) cadence), 4-wave body (wave wv owns nodes
// 16wv..16wv+15, lane = 16-term kc-chunk partial, fold shfl_xor(16,32)),
// multiplicative renorm u=p*rcp(rho), LS+=log(rho) off-path.
//
// Edge layout: e in [0,64): source->layer1 ; e = 64 + L*4096 + a*64 + b ;
// e = 258112 + j: layer64 node j -> sink.

typedef float v2f   __attribute__((ext_vector_type(2)));
typedef float f32x4 __attribute__((ext_vector_type(4)));
typedef unsigned int u32x4 __attribute__((ext_vector_type(4)));

#define NLV 63
#define NPACK (63 * 2048)            // packed u32 words (8KB/level)
#define SINK_BASE (64 + 63 * 4096)   // 258112
#define NPB 256

// ---------------------------------------------------------------------------
// prep (R8 verbatim, proven absmax 0.0): word f = L*2048 + h*1024 + t*4 + q,
// t in [0,256): kc=(t&63)>>4, bb=16*(t>>6)+(t&15), pair k = 16kc+2*(4h+q):
// packs bf16(exp(-w[e0])) | bf16(exp(-w[e0+64]))<<16, e0 = 64+L*4096+k*64+bb.
// Seq thread t reads its 2 quads at bytes L*8192 + t*16 and +4096. Coalesced.
// Plus 256 block partials of sum(w*gold).
__global__ __launch_bounds__(512)
void prep_kernel(const int* __restrict__ g, const float* __restrict__ w,
                 unsigned int* __restrict__ wpk, float* __restrict__ partial, int E) {
    const int f = blockIdx.x * blockDim.x + threadIdx.x;
    if (f < NPACK) {
        const int L = f >> 11;
        const int r = f & 2047;
        const int h = (r >> 10) & 1;
        const int t = (r >> 2) & 255;
        const int q = r & 3;
        const int wvp = t >> 6, ls = t & 63;
        const int kcp = ls >> 4, bp = 16 * wvp + (ls & 15);
        const int k = 16 * kcp + 2 * (4 * h + q);
        const int e0 = 64 + L * 4096 + k * 64 + bp;
        const float x0 = __expf(-w[e0]);
        const float x1 = __expf(-w[e0 + 64]);
        uint32_t u0 = __float_as_uint(x0); u0 = (u0 + 0x7fffu + ((u0 >> 16) & 1u)) >> 16;
        uint32_t u1 = __float_as_uint(x1); u1 = (u1 + 0x7fffu + ((u1 >> 16) & 1u)) >> 16;
        wpk[f] = u0 | (u1 << 16);
    }
    const bool is64 = (g[1] == 0);
    float s = 0.f;
    const int stride = gridDim.x * blockDim.x;
    for (int e = f; e < E; e += stride) {
        const int idx = 3 * e + 2;
        const int gv = is64 ? g[2 * idx] : g[idx];
        s += w[e] * (float)gv;
    }
    #pragma unroll
    for (int dd = 1; dd < 64; dd <<= 1) s += __shfl_xor(s, dd, 64);
    __shared__ float lsm[8];
    const int wv = threadIdx.x >> 6, ln = threadIdx.x & 63;
    if (ln == 0) lsm[wv] = s;
    __syncthreads();
    if (threadIdx.x == 0) {
        float tt = 0.f;
        #pragma unroll
        for (int i = 0; i < 8; ++i) tt += lsm[i];
        partial[blockIdx.x] = tt;
    }
}

// ---------------------------------------------------------------------------
// seq: 256 threads / 4 waves. Wave wv owns nodes 16wv..16wv+15; lane computes
// the 16-term k-chunk (kc) partial for b=16wv+(l&15); fold shfl_xor(16,32).
__global__ __launch_bounds__(256, 1)
void seq_kernel(const float* __restrict__ w, const unsigned int* __restrict__ wpk,
                const float* __restrict__ partial, float* __restrict__ out) {
    __shared__ __align__(16) float ubuf[2][64];
    __shared__ float P[2];
    __shared__ float slds[64];

    const int tid = threadIdx.x;
    const int wv = tid >> 6, l = tid & 63;
    const int kc = l >> 4;
    const int bb = 16 * wv + (l & 15);

    // compiler-visible loads, pinned complete before the counted-asm stream
    const float z10 = -w[0];
    float LS = z10;
    float uf = __expf(-w[bb] - z10);       // u_1[bb]; u_1[0] = 1
    float wsink = w[SINK_BASE + bb];
    float gs = 0.f;
    #pragma unroll
    for (int i = 0; i < 4; ++i) gs += partial[l + (i << 6)];
    asm volatile("" : "+v"(LS), "+v"(uf), "+v"(wsink), "+v"(gs));

    if (l < 16) ubuf[0][bb] = uf;
    if (tid == 0) P[0] = 1.0f;

    const uint32_t voff  = (uint32_t)tid * 16u;
    const uint32_t voff2 = voff + 4096u;
    uintptr_t bcur = (uintptr_t)wpk;

    u32x4 q0a, q0b, q1a, q1b, q2a, q2b, q3a, q3b, q4a, q4b;
    u32x4 q5a, q5b, q6a, q6b, q7a, q7b, q8a, q8b, q9a, q9b;

#define LD1(DST, VO)                                                           \
    asm volatile("global_load_dwordx4 %0, %1, %2"                              \
                 : "=v"(DST) : "v"(VO), "s"(bcur))

#define ISSUE(QA, QB) do { LD1(QA, voff); LD1(QB, voff2); bcur += 8192u; } while (0)

#define BAR() do {                                                             \
    asm volatile("s_waitcnt lgkmcnt(0)" ::: "memory");                         \
    __builtin_amdgcn_s_barrier();                                              \
} while (0)

// body t: CB = t&1. Reads ubuf[CB]/P[CB], writes ubuf[CB^1]/P[CB^1].
// u/rho reads issued BEFORE the vmcnt wait (LDS latency overlaps W stall);
// fmas held below the wait by the "+v" pin's data dependence on QA/QB.
#define BODY(QA, QB, CB, WSTR, DOISS) {                                        \
    const float rho = P[CB];                                                   \
    const f32x4* uqp = (const f32x4*)ubuf[CB];                                 \
    f32x4 uu[4];                                                               \
    uu[0] = uqp[4 * kc + 0];                                                   \
    uu[1] = uqp[4 * kc + 1];                                                   \
    uu[2] = uqp[4 * kc + 2];                                                   \
    uu[3] = uqp[4 * kc + 3];                                                   \
    asm volatile("s_waitcnt vmcnt(" WSTR ")" ::: "memory");                    \
    __builtin_amdgcn_sched_barrier(0);                                         \
    asm volatile("" : "+v"(QA), "+v"(QB));                                     \
    float rc;                                                                  \
    asm("v_rcp_f32 %0, %1" : "=v"(rc) : "v"(rho));                             \
    v2f acc = {0.f, 0.f};                                                      \
    _Pragma("unroll")                                                          \
    for (int m = 0; m < 4; ++m) {                                              \
        _Pragma("unroll")                                                      \
        for (int pp = 0; pp < 2; ++pp) {                                       \
            const int j2 = 2 * m + pp;                                         \
            const unsigned int wd = (j2 < 4) ? QA[j2] : QB[j2 - 4];            \
            v2f wp, up;                                                        \
            wp[0] = __uint_as_float(wd << 16);                                 \
            wp[1] = __uint_as_float(wd & 0xffff0000u);                         \
            up[0] = uu[m][2 * pp]; up[1] = uu[m][2 * pp + 1];                  \
            acc = __builtin_elementwise_fma(wp, up, acc);                      \
        }                                                                      \
    }                                                                          \
    float p = acc[0] + acc[1];                                                 \
    p += __shfl_xor(p, 16, 64);                                                \
    p += __shfl_xor(p, 32, 64);           /* p = y[bb] in all lanes */         \
    uf = p * rc;                                                               \
    if (l < 16) ubuf[(CB) ^ 1][bb] = uf;                                       \
    if (tid == 0) P[(CB) ^ 1] = uf;                                            \
    LS += __logf(rho);                    /* off critical path */              \
    if (DOISS) ISSUE(QA, QB);                                                  \
    BAR();                                                                     \
}

    // prologue: levels 0..9 in flight (20 loads)
    ISSUE(q0a, q0b); ISSUE(q1a, q1b); ISSUE(q2a, q2b); ISSUE(q3a, q3b);
    ISSUE(q4a, q4b); ISSUE(q5a, q5b); ISSUE(q6a, q6b); ISSUE(q7a, q7b);
    ISSUE(q8a, q8b); ISSUE(q9a, q9b);
    BAR();             // ubuf[0]/P[0] visible

    // bodies 0..49 (5 x 10-body rotation); body t consumes level t, issues t+10
    #pragma unroll 1
    for (int it = 0; it < 5; ++it) {
        BODY(q0a, q0b, 0, "18", 1)
        BODY(q1a, q1b, 1, "18", 1)
        BODY(q2a, q2b, 0, "18", 1)
        BODY(q3a, q3b, 1, "18", 1)
        BODY(q4a, q4b, 0, "18", 1)
        BODY(q5a, q5b, 1, "18", 1)
        BODY(q6a, q6b, 0, "18", 1)
        BODY(q7a, q7b, 1, "18", 1)
        BODY(q8a, q8b, 0, "18", 1)
        BODY(q9a, q9b, 1, "18", 1)
    }
    // peeled tail: bodies 50..62; last issue at body 52 (level 62);
    // exact waits leave ZERO loads in flight after body 62.
    BODY(q0a, q0b, 0, "18", 1)   // 50 -> L60
    BODY(q1a, q1b, 1, "18", 1)   // 51 -> L61
    BODY(q2a, q2b, 0, "18", 1)   // 52 -> L62
    BODY(q3a, q3b, 1, "18", 0)   // 53
    BODY(q4a, q4b, 0, "16", 0)   // 54
    BODY(q5a, q5b, 1, "14", 0)   // 55
    BODY(q6a, q6b, 0, "12", 0)   // 56
    BODY(q7a, q7b, 1, "10", 0)   // 57
    BODY(q8a, q8b, 0, "8",  0)   // 58
    BODY(q9a, q9b, 1, "6",  0)   // 59
    BODY(q0a, q0b, 0, "4",  0)   // 60
    BODY(q1a, q1b, 1, "2",  0)   // 61
    BODY(q2a, q2b, 0, "0",  0)   // 62

    // sink fold staging: m[bb] = LS + log(uf) - wsink
    const float m0 = LS + __logf(uf) - wsink;
    if (l < 16) slds[bb] = m0;
    BAR();

    if (wv == 0) {
        float m = slds[l];
        float s = 1.0f;
        #pragma unroll
        for (int d = 1; d < 64; d <<= 1) {
            const float om = __shfl_xor(m, d, 64);
            const float os = __shfl_xor(s, d, 64);
            const float nm = fmaxf(m, om);
            s = __expf(m - nm) * s + __expf(om - nm) * os;
            m = nm;
        }
        const float vsink = m + __logf(s);
        #pragma unroll
        for (int d = 1; d < 64; d <<= 1) gs += __shfl_xor(gs, d, 64);
        if (l == 0) out[0] = gs + vsink;
    }
}

extern "C" void kernel_launch(void* const* d_in, const int* in_sizes, int n_in,
                              void* d_out, int out_size, void* d_ws, size_t ws_size,
                              hipStream_t stream) {
    const int*   g = (const int*)d_in[0];
    const float* w = (const float*)d_in[1];
    float* out     = (float*)d_out;
    unsigned int* wpk = (unsigned int*)d_ws;        // 129024 u32
    float* partial = (float*)(wpk + NPACK);         // 256 floats
    const int E = in_sizes[0] / 3;                  // 258176

    prep_kernel<<<NPB, 512, 0, stream>>>(g, w, wpk, partial, E);
    seq_kernel<<<1, 256, 0, stream>>>(w, wpk, partial, out);
}

// Round 19
// 22.708 us; speedup vs baseline: 1.9814x; 1.2389x over previous
//
#include <hip/hip_runtime.h>
#include <hip/hip_bf16.h>
#include <cstdint>

// GraphLoss: layered lattice DAG (64 layers x 64 nodes, dense bipartite).
// result = sum(w*gold) + logsumexp over all source->sink paths of (-path weight).
//
// R19: PARALLEL LEVEL-FUSION. prep wgs 0..15 each compute the f32 product
// P_g = M_{4g}·M_{4g+1}·M_{4g+2}(·M_{4g+3}) of 4 (g=15: 3) adjacent level
// matrices in LDS and pack it as bf16 pairs in the R8-proven wpk layout.
// The proven seq kernel (R14/R18 structure, untouched hazard discipline)
// then runs 16 chain steps instead of 63. Sync between fusion and chain =
// kernel launch order on the stream (the only sync that has never failed).
// wgs 16..255 (240) do the gold reduction in parallel.
//
// seq hazard rules (R3-R7, all kept): counted vmcnt only on inline-asm load
// targets; no dummy loads; peeled tail 18/16/../0 -> ZERO in flight at exit;
// "+v" pin after each wait; sched_barrier(0) fences; raw s_barrier +
// lgkmcnt(0) cadence; multiplicative renorm u=p*rcp(rho), LS+=log(rho).
//
// Edge layout: e in [0,64): source->layer1 ; e = 64 + L*4096 + a*64 + b ;
// e = 258112 + j: layer64 node j -> sink.

typedef float v2f   __attribute__((ext_vector_type(2)));
typedef float f32x4 __attribute__((ext_vector_type(4)));
typedef unsigned int u32x4 __attribute__((ext_vector_type(4)));

#define NSTEP 16
#define SINK_BASE (64 + 63 * 4096)   // 258112
#define NGOLD 240
#define LDSTR 68                     // padded LDS row stride (f32 words)

// ---------------------------------------------------------------------------
// prep: 256 wgs x 256 thr. wgs 0..15: fused products + R8-layout bf16 pack.
// wgs 16..255: gold partials. Pack layout (R8-proven, seq reads it verbatim):
//   block g, word h*1024 + t*4 + q packs bf16(P[k][bb])|bf16(P[k+1][bb])<<16,
//   kc=(t&63)>>4, bb=16*(t>>6)+(t&15), k=16kc+2*(4h+q).
__global__ __launch_bounds__(256)
void prep_kernel(const int* __restrict__ g, const float* __restrict__ w,
                 unsigned int* __restrict__ wpk, float* __restrict__ partial, int E) {
    const int bid = blockIdx.x, t = threadIdx.x;

    if (bid < 16) {
        __shared__ __align__(16) float Xs[64 * LDSTR];
        __shared__ __align__(16) float Ys[64 * LDSTR];
        __shared__ __align__(16) float Zs[64 * LDSTR];
        const int gg = bid;
        const int L0 = 4 * gg;
        const int ng = (gg == 15) ? 3 : 4;

        // load+exp M_{L0} -> Xs (coalesced global, scattered-but-cheap LDS)
        {
            const float* src = w + 64 + L0 * 4096;
            #pragma unroll
            for (int j = 0; j < 16; ++j) {
                const int idx = j * 256 + t;
                Xs[(idx >> 6) * LDSTR + (idx & 63)] = __expf(-src[idx]);
            }
        }
        float* cur = Xs;
        float* oth = Zs;
        const int rb = 4 * (t >> 4);     // 4 consecutive output rows
        const int c0 = 4 * (t & 15);     // 4 output cols

        #pragma unroll 1
        for (int m = 1; m < ng; ++m) {
            const float* src = w + 64 + (L0 + m) * 4096;
            #pragma unroll
            for (int j = 0; j < 16; ++j) {
                const int idx = j * 256 + t;
                Ys[(idx >> 6) * LDSTR + (idx & 63)] = __expf(-src[idx]);
            }
            __syncthreads();             // X/prev product + Y ready
            // oth = cur · Ys   (each thread: 4 rows x 4 cols)
            f32x4 a0 = {0,0,0,0}, a1 = {0,0,0,0}, a2 = {0,0,0,0}, a3 = {0,0,0,0};
            #pragma unroll 4
            for (int k = 0; k < 64; ++k) {
                const f32x4 y = *(const f32x4*)&Ys[k * LDSTR + c0];
                const float x0 = cur[(rb + 0) * LDSTR + k];
                const float x1 = cur[(rb + 1) * LDSTR + k];
                const float x2 = cur[(rb + 2) * LDSTR + k];
                const float x3 = cur[(rb + 3) * LDSTR + k];
                const f32x4 s0 = {x0, x0, x0, x0};
                const f32x4 s1 = {x1, x1, x1, x1};
                const f32x4 s2 = {x2, x2, x2, x2};
                const f32x4 s3 = {x3, x3, x3, x3};
                a0 = __builtin_elementwise_fma(s0, y, a0);
                a1 = __builtin_elementwise_fma(s1, y, a1);
                a2 = __builtin_elementwise_fma(s2, y, a2);
                a3 = __builtin_elementwise_fma(s3, y, a3);
            }
            *(f32x4*)&oth[(rb + 0) * LDSTR + c0] = a0;
            *(f32x4*)&oth[(rb + 1) * LDSTR + c0] = a1;
            *(f32x4*)&oth[(rb + 2) * LDSTR + c0] = a2;
            *(f32x4*)&oth[(rb + 3) * LDSTR + c0] = a3;
            __syncthreads();             // product done before Y reuse
            float* tmp = cur; cur = oth; oth = tmp;
        }

        // pack cur -> wpk block g (R8 layout)
        const int kc = (t & 63) >> 4;
        const int bb = 16 * (t >> 6) + (t & 15);
        #pragma unroll
        for (int h = 0; h < 2; ++h) {
            #pragma unroll
            for (int q = 0; q < 4; ++q) {
                const int k = 16 * kc + 2 * (4 * h + q);
                const float x0 = cur[k * LDSTR + bb];
                const float x1 = cur[(k + 1) * LDSTR + bb];
                uint32_t u0 = __float_as_uint(x0); u0 = (u0 + 0x7fffu + ((u0 >> 16) & 1u)) >> 16;
                uint32_t u1 = __float_as_uint(x1); u1 = (u1 + 0x7fffu + ((u1 >> 16) & 1u)) >> 16;
                wpk[gg * 2048 + h * 1024 + t * 4 + q] = u0 | (u1 << 16);
            }
        }
        return;
    }

    // -------- gold partial (240 wgs) --------
    const int gid = bid - 16;
    const bool is64 = (g[1] == 0);
    float s = 0.f;
    for (int e = gid * 256 + t; e < E; e += NGOLD * 256) {
        const int idx = 3 * e + 2;
        const int gv = is64 ? g[2 * idx] : g[idx];
        s += w[e] * (float)gv;
    }
    #pragma unroll
    for (int dd = 1; dd < 64; dd <<= 1) s += __shfl_xor(s, dd, 64);
    __shared__ float lsm[4];
    const int wv = t >> 6, ln = t & 63;
    if (ln == 0) lsm[wv] = s;
    __syncthreads();
    if (t == 0) partial[gid] = lsm[0] + lsm[1] + lsm[2] + lsm[3];
}

// ---------------------------------------------------------------------------
// seq: 256 threads / 4 waves (R18 verbatim body), 16 fused steps.
__global__ __launch_bounds__(256, 1)
void seq_kernel(const float* __restrict__ w, const unsigned int* __restrict__ wpk,
                const float* __restrict__ partial, float* __restrict__ out) {
    __shared__ __align__(16) float ubuf[2][64];
    __shared__ float P[2];
    __shared__ float slds[64];

    const int tid = threadIdx.x;
    const int wv = tid >> 6, l = tid & 63;
    const int kc = l >> 4;
    const int bb = 16 * wv + (l & 15);

    // compiler-visible loads, pinned complete before the counted-asm stream
    const float z10 = -w[0];
    float LS = z10;
    float uf = __expf(-w[bb] - z10);       // u_1[bb]; u_1[0] = 1
    float wsink = w[SINK_BASE + bb];
    float gs = 0.f;
    #pragma unroll
    for (int i = 0; i < 3; ++i) gs += partial[l + (i << 6)];
    if (l < NGOLD - 192) gs += partial[l + 192];
    asm volatile("" : "+v"(LS), "+v"(uf), "+v"(wsink), "+v"(gs));

    if (l < 16) ubuf[0][bb] = uf;
    if (tid == 0) P[0] = 1.0f;

    const uint32_t voff  = (uint32_t)tid * 16u;
    const uint32_t voff2 = voff + 4096u;
    uintptr_t bcur = (uintptr_t)wpk;

    u32x4 q0a, q0b, q1a, q1b, q2a, q2b, q3a, q3b, q4a, q4b;
    u32x4 q5a, q5b, q6a, q6b, q7a, q7b, q8a, q8b, q9a, q9b;

#define LD1(DST, VO)                                                           \
    asm volatile("global_load_dwordx4 %0, %1, %2"                              \
                 : "=v"(DST) : "v"(VO), "s"(bcur))

#define ISSUE(QA, QB) do { LD1(QA, voff); LD1(QB, voff2); bcur += 8192u; } while (0)

#define BAR() do {                                                             \
    asm volatile("s_waitcnt lgkmcnt(0)" ::: "memory");                         \
    __builtin_amdgcn_s_barrier();                                              \
} while (0)

// body t: CB = t&1. u/rho reads above the wait (R18); fmas below via pin.
#define BODY(QA, QB, CB, WSTR, DOISS) {                                        \
    const float rho = P[CB];                                                   \
    const f32x4* uqp = (const f32x4*)ubuf[CB];                                 \
    f32x4 uu[4];                                                               \
    uu[0] = uqp[4 * kc + 0];                                                   \
    uu[1] = uqp[4 * kc + 1];                                                   \
    uu[2] = uqp[4 * kc + 2];                                                   \
    uu[3] = uqp[4 * kc + 3];                                                   \
    asm volatile("s_waitcnt vmcnt(" WSTR ")" ::: "memory");                    \
    __builtin_amdgcn_sched_barrier(0);                                         \
    asm volatile("" : "+v"(QA), "+v"(QB));                                     \
    float rc;                                                                  \
    asm("v_rcp_f32 %0, %1" : "=v"(rc) : "v"(rho));                             \
    v2f acc = {0.f, 0.f};                                                      \
    _Pragma("unroll")                                                          \
    for (int m = 0; m < 4; ++m) {                                              \
        _Pragma("unroll")                                                      \
        for (int pp = 0; pp < 2; ++pp) {                                       \
            const int j2 = 2 * m + pp;                                         \
            const unsigned int wd = (j2 < 4) ? QA[j2] : QB[j2 - 4];            \
            v2f wp, up;                                                        \
            wp[0] = __uint_as_float(wd << 16);                                 \
            wp[1] = __uint_as_float(wd & 0xffff0000u);                         \
            up[0] = uu[m][2 * pp]; up[1] = uu[m][2 * pp + 1];                  \
            acc = __builtin_elementwise_fma(wp, up, acc);                      \
        }                                                                      \
    }                                                                          \
    float p = acc[0] + acc[1];                                                 \
    p += __shfl_xor(p, 16, 64);                                                \
    p += __shfl_xor(p, 32, 64);           /* p = y[bb] in all lanes */         \
    uf = p * rc;                                                               \
    if (l < 16) ubuf[(CB) ^ 1][bb] = uf;                                       \
    if (tid == 0) P[(CB) ^ 1] = uf;                                            \
    LS += __logf(rho);                    /* off critical path */              \
    if (DOISS) ISSUE(QA, QB);                                                  \
    BAR();                                                                     \
}

    // prologue: steps 0..9 in flight (20 loads)
    ISSUE(q0a, q0b); ISSUE(q1a, q1b); ISSUE(q2a, q2b); ISSUE(q3a, q3b);
    ISSUE(q4a, q4b); ISSUE(q5a, q5b); ISSUE(q6a, q6b); ISSUE(q7a, q7b);
    ISSUE(q8a, q8b); ISSUE(q9a, q9b);
    BAR();             // ubuf[0]/P[0] visible

    // 16 bodies; issues end at body 5 (step 15); exact peeled waits leave
    // ZERO loads in flight after body 15.
    BODY(q0a, q0b, 0, "18", 1)   // 0  -> issues S10
    BODY(q1a, q1b, 1, "18", 1)   // 1  -> S11
    BODY(q2a, q2b, 0, "18", 1)   // 2  -> S12
    BODY(q3a, q3b, 1, "18", 1)   // 3  -> S13
    BODY(q4a, q4b, 0, "18", 1)   // 4  -> S14
    BODY(q5a, q5b, 1, "18", 1)   // 5  -> S15 (last issue)
    BODY(q6a, q6b, 0, "18", 0)   // 6
    BODY(q7a, q7b, 1, "16", 0)   // 7
    BODY(q8a, q8b, 0, "14", 0)   // 8
    BODY(q9a, q9b, 1, "12", 0)   // 9
    BODY(q0a, q0b, 0, "10", 0)   // 10
    BODY(q1a, q1b, 1, "8",  0)   // 11
    BODY(q2a, q2b, 0, "6",  0)   // 12
    BODY(q3a, q3b, 1, "4",  0)   // 13
    BODY(q4a, q4b, 0, "2",  0)   // 14
    BODY(q5a, q5b, 1, "0",  0)   // 15

    // sink fold staging: m[bb] = LS + log(uf) - wsink
    const float m0 = LS + __logf(uf) - wsink;
    if (l < 16) slds[bb] = m0;
    BAR();

    if (wv == 0) {
        float m = slds[l];
        float s = 1.0f;
        #pragma unroll
        for (int d = 1; d < 64; d <<= 1) {
            const float om = __shfl_xor(m, d, 64);
            const float os = __shfl_xor(s, d, 64);
            const float nm = fmaxf(m, om);
            s = __expf(m - nm) * s + __expf(om - nm) * os;
            m = nm;
        }
        const float vsink = m + __logf(s);
        #pragma unroll
        for (int d = 1; d < 64; d <<= 1) gs += __shfl_xor(gs, d, 64);
        if (l == 0) out[0] = gs + vsink;
    }
}

extern "C" void kernel_launch(void* const* d_in, const int* in_sizes, int n_in,
                              void* d_out, int out_size, void* d_ws, size_t ws_size,
                              hipStream_t stream) {
    const int*   g = (const int*)d_in[0];
    const float* w = (const float*)d_in[1];
    float* out     = (float*)d_out;
    unsigned int* wpk = (unsigned int*)d_ws;        // 16*2048 u32
    float* partial = (float*)(wpk + 16 * 2048);     // 240 floats
    const int E = in_sizes[0] / 3;                  // 258176

    prep_kernel<<<256, 256, 0, stream>>>(g, w, wpk, partial, E);
    seq_kernel<<<1, 256, 0, stream>>>(w, wpk, partial, out);
}